// Round 6
// baseline (91.564 us; speedup 1.0000x reference)
//
#include <hip/hip_runtime.h>

// B=4, L=128, D=256, NUM_KNOTS=64, HEAD_DIM=4 -> N = 8192 knots/batch, 512 rows.
#define NQ 8192
#define BLROWS 512
#define DIM 256
#define KSLICES 16

// 0.5 (= 1/sqrt(4)) * log2(e): fold softmax scale + base-2 conversion into Q.
#define QSCALE 0.7213475204444817f

typedef float v2f __attribute__((ext_vector_type(2)));

__device__ __forceinline__ float ex2(float x) {
#if __has_builtin(__builtin_amdgcn_exp2f)
    return __builtin_amdgcn_exp2f(x);
#else
    return exp2f(x);
#endif
}

// ---------------------------------------------------------------------------
// QKV projection: C[M,256] = (x[M,256] @ W^T) * scale. 4 rows/block.
// ---------------------------------------------------------------------------
__global__ __launch_bounds__(256) void qkv_proj(
    const float* __restrict__ x,
    const float* __restrict__ Wq, const float* __restrict__ Wk,
    const float* __restrict__ Wv,
    float* __restrict__ Qb, float* __restrict__ Kb, float* __restrict__ Vb)
{
    const int m = blockIdx.y;
    const float* W = (m == 0) ? Wq : (m == 1) ? Wk : Wv;
    float* C       = (m == 0) ? Qb : (m == 1) ? Kb : Vb;
    const float sc = (m == 0) ? QSCALE : 1.0f;
    const int j  = threadIdx.x;
    const int rb = blockIdx.x * 4;

    float acc[4] = {0.f, 0.f, 0.f, 0.f};
    const float4* __restrict__ W4 = reinterpret_cast<const float4*>(W + j * DIM);
    const float*  __restrict__ A0 = x + rb * DIM;

    #pragma unroll 4
    for (int d4 = 0; d4 < DIM / 4; ++d4) {
        const float4 w = W4[d4];
        #pragma unroll
        for (int r = 0; r < 4; ++r) {
            const float4 a = reinterpret_cast<const float4*>(A0 + r * DIM)[d4];
            acc[r] = fmaf(a.x, w.x, acc[r]);
            acc[r] = fmaf(a.y, w.y, acc[r]);
            acc[r] = fmaf(a.z, w.z, acc[r]);
            acc[r] = fmaf(a.w, w.w, acc[r]);
        }
    }
    #pragma unroll
    for (int r = 0; r < 4; ++r)
        C[(rb + r) * DIM + j] = acc[r] * sc;
}

// ---------------------------------------------------------------------------
// Attention partials. Grid (32 qt, 16 ks, 4 b) = 2048 blocks, 256 threads
// (4 waves). K/V slice (512 keys, 16 KB) is staged in LDS once; each wave
// walks its 128-key quarter via wave-uniform ds_read_b128 (broadcast,
// conflict-free, IN-ORDER completion -> fine-grained lgkmcnt pipelining,
// unlike s_load which forces lgkmcnt(0) drains). Each thread owns 4 queries
// packed as 2 float2 pairs (v_pk_fma_f32). No-max softmax: p = exp2(s)
// (Q pre-scaled into log2 domain). Cross-wave reduction per component via a
// 4 KB red2 buffer (keeps LDS at 20 KB -> 8 blocks/CU).
// P layout: P[b][ks][c in 0..4][n].
// ---------------------------------------------------------------------------
__global__ __launch_bounds__(256, 6) void attn_partial(
    const float* __restrict__ Q, const float* __restrict__ K,
    const float* __restrict__ V, float* __restrict__ P)
{
    __shared__ float4 KV[1024];       // K: [0..511], V: [512..1023] -> 16 KB
    __shared__ float  red2[4][256];   // 4 KB

    const int t    = threadIdx.x;
    const int lane = t & 63;
    const int w    = __builtin_amdgcn_readfirstlane(t >> 6); // 0..3
    const int qt   = blockIdx.x;         // 0..31 (256 queries each)
    const int ks   = blockIdx.y;         // 0..15 (512 keys each)
    const int b    = blockIdx.z;         // 0..3

    // stage K/V slice: 1024 float4, 4 per thread, coalesced
    {
        const float4* __restrict__ Kg = reinterpret_cast<const float4*>(K) + b * NQ + ks * 512;
        const float4* __restrict__ Vg = reinterpret_cast<const float4*>(V) + b * NQ + ks * 512;
        KV[t]             = Kg[t];
        KV[t + 256]       = Kg[t + 256];
        KV[512 + t]       = Vg[t];
        KV[512 + t + 256] = Vg[t + 256];
    }

    // load Q while staging is in flight
    const float4* __restrict__ Qp = reinterpret_cast<const float4*>(Q) + b * NQ + qt * 256;
    v2f qx[2], qy[2], qz[2], qw[2];
    #pragma unroll
    for (int p = 0; p < 2; ++p) {
        const float4 t0 = Qp[(2 * p)     * 64 + lane];
        const float4 t1 = Qp[(2 * p + 1) * 64 + lane];
        qx[p] = v2f{t0.x, t1.x};
        qy[p] = v2f{t0.y, t1.y};
        qz[p] = v2f{t0.z, t1.z};
        qw[p] = v2f{t0.w, t1.w};
    }
    v2f a0[2], a1[2], a2[2], a3[2], ls[2];
    #pragma unroll
    for (int p = 0; p < 2; ++p) {
        a0[p] = v2f{0.f, 0.f}; a1[p] = v2f{0.f, 0.f};
        a2[p] = v2f{0.f, 0.f}; a3[p] = v2f{0.f, 0.f};
        ls[p] = v2f{0.f, 0.f};
    }
    __syncthreads();

    const float4* __restrict__ Kl = &KV[w * 128];
    const float4* __restrict__ Vl = &KV[512 + w * 128];

    #pragma unroll 4
    for (int j = 0; j < 128; ++j) {
        const float4 k4 = Kl[j];   // uniform addr -> ds_read_b128 broadcast
        const float4 v4 = Vl[j];
        #pragma unroll
        for (int p = 0; p < 2; ++p) {
            v2f s = qx[p] * k4.x;
            s = __builtin_elementwise_fma(qy[p], v2f{k4.y, k4.y}, s);
            s = __builtin_elementwise_fma(qz[p], v2f{k4.z, k4.z}, s);
            s = __builtin_elementwise_fma(qw[p], v2f{k4.w, k4.w}, s);
            const v2f e = v2f{ex2(s[0]), ex2(s[1])};
            ls[p] += e;
            a0[p] = __builtin_elementwise_fma(e, v2f{v4.x, v4.x}, a0[p]);
            a1[p] = __builtin_elementwise_fma(e, v2f{v4.y, v4.y}, a1[p]);
            a2[p] = __builtin_elementwise_fma(e, v2f{v4.z, v4.z}, a2[p]);
            a3[p] = __builtin_elementwise_fma(e, v2f{v4.w, v4.w}, a3[p]);
        }
    }

    // Per-component cross-wave reduction through the 4 KB red2 buffer.
    float* __restrict__ Pb = P + (size_t)((b * KSLICES + ks) * 5) * NQ + qt * 256;
    __syncthreads();   // all waves done with KV reads before red2 reuse races? (red2 separate; barrier orders store rounds)

#define RED_ROUND(ARR, cidx)                                              \
    {                                                                     \
        _Pragma("unroll")                                                 \
        for (int p = 0; p < 2; ++p) {                                     \
            _Pragma("unroll")                                             \
            for (int e = 0; e < 2; ++e)                                   \
                red2[w][(2 * p + e) * 64 + lane] = ARR[p][e];             \
        }                                                                 \
        __syncthreads();                                                  \
        Pb[(cidx) * NQ + t] =                                             \
            red2[0][t] + red2[1][t] + red2[2][t] + red2[3][t];            \
        __syncthreads();                                                  \
    }

    RED_ROUND(ls, 0)
    RED_ROUND(a0, 1)
    RED_ROUND(a1, 2)
    RED_ROUND(a2, 3)
    RED_ROUND(a3, 4)
#undef RED_ROUND
}

// ---------------------------------------------------------------------------
// Fused merge + output projection. Grid 128 blocks x 256 thr; block = 4 rows
// = 256 knots. Phase 1: merge 16 key-slice partials, normalize, stash AO
// tile in LDS. Phase 2: out = AO @ Wo^T + bo.
// ---------------------------------------------------------------------------
__global__ __launch_bounds__(256) void merge_oproj(
    const float* __restrict__ P, const float* __restrict__ Wo,
    const float* __restrict__ bo, float* __restrict__ out)
{
    __shared__ float aoL[4][DIM];      // 4 KB

    const int rb = blockIdx.x * 4;     // first row (0..508)
    const int b  = rb >> 7;            // batch
    const int n0 = (rb & 127) * 64;    // first knot within batch
    const int t  = threadIdx.x;        // knot offset 0..255

    {
        float sums[5] = {0.f, 0.f, 0.f, 0.f, 0.f};
        const float* __restrict__ Pb = P + (size_t)(b * KSLICES * 5) * NQ + n0 + t;
        #pragma unroll
        for (int s = 0; s < KSLICES; ++s) {
            #pragma unroll
            for (int c = 0; c < 5; ++c)
                sums[c] += Pb[(s * 5 + c) * NQ];
        }
        const float inv = 1.0f / sums[0];
        const int row = t >> 6;
        const int d0  = (t & 63) * 4;
        aoL[row][d0 + 0] = sums[1] * inv;
        aoL[row][d0 + 1] = sums[2] * inv;
        aoL[row][d0 + 2] = sums[3] * inv;
        aoL[row][d0 + 3] = sums[4] * inv;
    }
    __syncthreads();

    const int j = t;
    float acc[4] = {0.f, 0.f, 0.f, 0.f};
    const float4* __restrict__ W4 = reinterpret_cast<const float4*>(Wo + j * DIM);
    #pragma unroll 4
    for (int d4 = 0; d4 < DIM / 4; ++d4) {
        const float4 wv = W4[d4];
        #pragma unroll
        for (int r = 0; r < 4; ++r) {
            const float4 a = reinterpret_cast<const float4*>(&aoL[r][0])[d4];
            acc[r] = fmaf(a.x, wv.x, acc[r]);
            acc[r] = fmaf(a.y, wv.y, acc[r]);
            acc[r] = fmaf(a.z, wv.z, acc[r]);
            acc[r] = fmaf(a.w, wv.w, acc[r]);
        }
    }
    const float bias = bo[j];
    #pragma unroll
    for (int r = 0; r < 4; ++r)
        out[(rb + r) * DIM + j] = acc[r] + bias;
}

extern "C" void kernel_launch(void* const* d_in, const int* in_sizes, int n_in,
                              void* d_out, int out_size, void* d_ws, size_t ws_size,
                              hipStream_t stream) {
    const float* x  = (const float*)d_in[0];
    const float* Wq = (const float*)d_in[1];
    const float* Wk = (const float*)d_in[2];
    const float* Wv = (const float*)d_in[3];
    const float* Wo = (const float*)d_in[4];
    const float* bo = (const float*)d_in[5];
    float* out = (float*)d_out;

    float* Qb = (float*)d_ws;              // 131072 f32
    float* Kb = Qb + BLROWS * DIM;         // 131072
    float* Vb = Kb + BLROWS * DIM;         // 131072
    float* P  = Vb + BLROWS * DIM;         // 4*16*5*8192 = 2,621,440 f32
    // total = 3,014,656 floats = 12.06 MB

    qkv_proj<<<dim3(128, 3), 256, 0, stream>>>(x, Wq, Wk, Wv, Qb, Kb, Vb);
    attn_partial<<<dim3(32, KSLICES, 4), 256, 0, stream>>>(Qb, Kb, Vb, P);
    merge_oproj<<<128, 256, 0, stream>>>(P, Wo, bo, out);
}